// Round 6
// baseline (114.305 us; speedup 1.0000x reference)
//
#include <hip/hip_runtime.h>

#define NN 4096
#define FIN 256
#define CC 256
#define NH 8

typedef __attribute__((ext_vector_type(8))) short short8;
typedef __attribute__((ext_vector_type(4))) float f32x4;
typedef __attribute__((ext_vector_type(4))) unsigned int u32x4;

__device__ __forceinline__ unsigned cvtpk_bf16(float lo, float hi) {
  unsigned r;
  asm("v_cvt_pk_bf16_f32 %0, %1, %2" : "=v"(r) : "v"(lo), "v"(hi));
  return r;
}

__device__ __forceinline__ unsigned short bf16rn(float x) {
  unsigned int u = __builtin_bit_cast(unsigned int, x);
  u += 0x7fffu + ((u >> 16) & 1u);
  return (unsigned short)(u >> 16);
}

// ---------------- K1: g = h@W, fused epilogue ----------------
// writes gT (bf16, [c=h*32+f][n]), spack[h][n]=(s_src, e^s, e^.2s, 0),
// dtrip blocked: [h][n>>3][3][8] = (-s_dst, e^sd, e^{0.2 sd}) per 8-node block
#define GROWS 8
__global__ __launch_bounds__(256) void k_gemm(
    const float* __restrict__ h, const float* __restrict__ W,
    const float* __restrict__ a, unsigned short* __restrict__ gT,
    float4* __restrict__ spack, float* __restrict__ dtrip) {
  __shared__ float hs[GROWS][FIN];
  const int r0 = blockIdx.x * GROWS;
  const int t = threadIdx.x;
#pragma unroll
  for (int idx = t; idx < GROWS * FIN / 4; idx += 256) {
    const int r = idx >> 6, c4 = idx & 63;
    *(float4*)&hs[r][c4 * 4] =
        *(const float4*)&h[(size_t)(r0 + r) * FIN + c4 * 4];
  }
  __syncthreads();
  const int c = t;
  float acc[GROWS];
#pragma unroll
  for (int r = 0; r < GROWS; ++r) acc[r] = 0.f;
  for (int k = 0; k < FIN; k += 4) {
    const float w0 = W[(size_t)(k + 0) * CC + c];
    const float w1 = W[(size_t)(k + 1) * CC + c];
    const float w2 = W[(size_t)(k + 2) * CC + c];
    const float w3 = W[(size_t)(k + 3) * CC + c];
#pragma unroll
    for (int r = 0; r < GROWS; ++r) {
      const float4 hv = *(const float4*)&hs[r][k];
      acc[r] += hv.x * w0 + hv.y * w1 + hv.z * w2 + hv.w * w3;
    }
  }
  const int f = c & 31, hh = c >> 5;
  const float aS = a[f], aD = a[32 + f];
  unsigned short gu[GROWS];
#pragma unroll
  for (int r = 0; r < GROWS; ++r) {
    float ps = acc[r] * aS, pd = acc[r] * aD;
#pragma unroll
    for (int m = 1; m < 32; m <<= 1) {
      ps += __shfl_xor(ps, m, 64);
      pd += __shfl_xor(pd, m, 64);
    }
    if (f == 0) {
      const int n = r0 + r;
      spack[(size_t)hh * NN + n] =
          make_float4(ps, __expf(ps), __expf(0.2f * ps), 0.f);
      const size_t db = ((size_t)hh * (NN / 8) + (n >> 3)) * 24 + (n & 7);
      dtrip[db] = -pd;
      dtrip[db + 8] = __expf(pd);
      dtrip[db + 16] = __expf(0.2f * pd);
    }
    gu[r] = bf16rn(acc[r]);
  }
  uint4 gv;
  gv.x = (unsigned)gu[0] | ((unsigned)gu[1] << 16);
  gv.y = (unsigned)gu[2] | ((unsigned)gu[3] << 16);
  gv.z = (unsigned)gu[4] | ((unsigned)gu[5] << 16);
  gv.w = (unsigned)gu[6] | ((unsigned)gu[7] << 16);
  *(uint4*)(gT + (size_t)c * NN + r0) = gv;
}

// ---------------- K2: barrier-free fused masked-softmax + MFMA PV ----------
// 256-thread blocks = 4 independent waves; wave w handles heads {2w, 2w+1}.
// No LDS, no __syncthreads. All streams software-pipelined one chunk ahead
// (named single-buffer prefetch; compiler emits counted vmcnt waits).
__global__ __launch_bounds__(256, 2) void k_attn(
    const int* __restrict__ adj, const unsigned short* __restrict__ gT,
    const float4* __restrict__ spack, const float* __restrict__ dtrip,
    float* __restrict__ acc_ws, float* __restrict__ l_ws,
    float* __restrict__ out, const int splits, const int direct) {
  const int lane = threadIdx.x & 63;
  const int w = threadIdx.x >> 6;
  const int il = lane & 15, q = lane >> 4;
  const int bx = blockIdx.x;
  const int sp = bx & (splits - 1);
  const int ib = bx / splits;
  const int i0 = ib * 32;
  const int jrange = NN / splits, j0b = sp * jrange;
  const int hbase = w * 2;

  // hoisted i-side scalars
  float ssv[2][2], e1v[2][2], e2v[2][2];
#pragma unroll
  for (int hp = 0; hp < 2; ++hp)
#pragma unroll
    for (int it = 0; it < 2; ++it) {
      const float4 v = spack[(size_t)(hbase + hp) * NN + i0 + it * 16 + il];
      ssv[hp][it] = v.x; e1v[hp][it] = v.y; e2v[hp][it] = v.z;
    }

  f32x4 acc[2][2][2];
  f32x4 lac[2][2];
#pragma unroll
  for (int hp = 0; hp < 2; ++hp)
#pragma unroll
    for (int it = 0; it < 2; ++it) {
#pragma unroll
      for (int r = 0; r < 4; ++r) lac[hp][it][r] = 0.f;
#pragma unroll
      for (int ft = 0; ft < 2; ++ft)
#pragma unroll
        for (int r = 0; r < 4; ++r) acc[hp][it][ft][r] = 0.f;
    }

  const short8 ones = {(short)0x3F80, (short)0x3F80, (short)0x3F80,
                       (short)0x3F80, (short)0x3F80, (short)0x3F80,
                       (short)0x3F80, (short)0x3F80};

  // hoisted row pointers
  const int* arow0 = adj + (size_t)(i0 + il) * NN;
  const int* arow1 = adj + (size_t)(i0 + 16 + il) * NN;
  const unsigned short* gr[2][2];
#pragma unroll
  for (int hp = 0; hp < 2; ++hp) {
    const int hh = hbase + hp;
    gr[hp][0] = gT + (size_t)(hh * 32 + il) * NN;
    gr[hp][1] = gT + (size_t)(hh * 32 + 16 + il) * NN;
  }
  const float* dbase[2];
#pragma unroll
  for (int hp = 0; hp < 2; ++hp)
    dbase[hp] =
        dtrip + ((size_t)(hbase + hp) * (NN / 8) + (j0b >> 3) + q) * 24;

  // --- prefetch state (single named buffers, overwritten after last use) ---
  int4 pa0, pa1, pa2, pa3;
  float4 Ad0, Ad1, Ad2, Ad3, Ad4, Ad5;  short8 Ab0, Ab1;  // hp = 0
  float4 Bd0, Bd1, Bd2, Bd3, Bd4, Bd5;  short8 Bb0, Bb1;  // hp = 1

#define ISSUE_ADJ(JQ)                        \
  pa0 = *(const int4*)&arow0[JQ];            \
  pa1 = *(const int4*)&arow0[(JQ) + 4];      \
  pa2 = *(const int4*)&arow1[JQ];            \
  pa3 = *(const int4*)&arow1[(JQ) + 4];

#define ISSUE_J(P, HP, JC)                                 \
  {                                                        \
    const float* dp_ = dbase[HP] + (size_t)(JC) * 96;      \
    P##d0 = *(const float4*)(dp_ + 0);                     \
    P##d1 = *(const float4*)(dp_ + 4);                     \
    P##d2 = *(const float4*)(dp_ + 8);                     \
    P##d3 = *(const float4*)(dp_ + 12);                    \
    P##d4 = *(const float4*)(dp_ + 16);                    \
    P##d5 = *(const float4*)(dp_ + 20);                    \
    const int jq_ = j0b + (JC) * 32 + q * 8;               \
    P##b0 = *(const short8*)&gr[HP][0][jq_];               \
    P##b1 = *(const short8*)&gr[HP][1][jq_];               \
  }

#define COMPUTE_HP(P, HP)                                                   \
  {                                                                         \
    const float nsd_[8] = {P##d0.x, P##d0.y, P##d0.z, P##d0.w,              \
                           P##d1.x, P##d1.y, P##d1.z, P##d1.w};             \
    const float e1j_[8] = {P##d2.x, P##d2.y, P##d2.z, P##d2.w,              \
                           P##d3.x, P##d3.y, P##d3.z, P##d3.w};             \
    const float e2j_[8] = {P##d4.x, P##d4.y, P##d4.z, P##d4.w,              \
                           P##d5.x, P##d5.y, P##d5.z, P##d5.w};             \
    _Pragma("unroll") for (int it = 0; it < 2; ++it) {                      \
      const float ssl = ssv[HP][it];                                        \
      const float ei1 = e1v[HP][it], ei2 = e2v[HP][it];                     \
      float wv[8];                                                          \
      _Pragma("unroll") for (int e = 0; e < 8; ++e) {                       \
        const bool pos = ssl > nsd_[e];                                     \
        wv[e] = (pos ? ei1 : ei2) * (pos ? e1j_[e] : e2j_[e]) * adf[it][e]; \
      }                                                                     \
      u32x4 uu;                                                             \
      _Pragma("unroll") for (int m = 0; m < 4; ++m)                         \
          uu[m] = cvtpk_bf16(wv[2 * m], wv[2 * m + 1]);                     \
      const short8 afr = __builtin_bit_cast(short8, uu);                    \
      acc[HP][it][0] = __builtin_amdgcn_mfma_f32_16x16x32_bf16(             \
          afr, P##b0, acc[HP][it][0], 0, 0, 0);                             \
      acc[HP][it][1] = __builtin_amdgcn_mfma_f32_16x16x32_bf16(             \
          afr, P##b1, acc[HP][it][1], 0, 0, 0);                             \
      lac[HP][it] = __builtin_amdgcn_mfma_f32_16x16x32_bf16(                \
          afr, ones, lac[HP][it], 0, 0, 0);                                 \
    }                                                                       \
  }

  const int nch = jrange / 32;
  ISSUE_ADJ(j0b + q * 8);
  ISSUE_J(A, 0, 0);
  ISSUE_J(B, 1, 0);

  for (int jc = 0; jc < nch; ++jc) {
    // consume adj -> float multipliers, then refill adj prefetch
    float adf[2][8];
    {
      const int4 a0 = pa0, a1 = pa1, a2 = pa2, a3 = pa3;
      adf[0][0] = (float)a0.x; adf[0][1] = (float)a0.y;
      adf[0][2] = (float)a0.z; adf[0][3] = (float)a0.w;
      adf[0][4] = (float)a1.x; adf[0][5] = (float)a1.y;
      adf[0][6] = (float)a1.z; adf[0][7] = (float)a1.w;
      adf[1][0] = (float)a2.x; adf[1][1] = (float)a2.y;
      adf[1][2] = (float)a2.z; adf[1][3] = (float)a2.w;
      adf[1][4] = (float)a3.x; adf[1][5] = (float)a3.y;
      adf[1][6] = (float)a3.z; adf[1][7] = (float)a3.w;
    }
    if (jc + 1 < nch) { ISSUE_ADJ(j0b + (jc + 1) * 32 + q * 8); }

    COMPUTE_HP(A, 0);
    if (jc + 1 < nch) ISSUE_J(A, 0, jc + 1);  // refill while hp1 computes
    COMPUTE_HP(B, 1);
    if (jc + 1 < nch) ISSUE_J(B, 1, jc + 1);  // refill while next adf/hp0 run
  }
#undef ISSUE_ADJ
#undef ISSUE_J
#undef COMPUTE_HP

  if (direct) {
#pragma unroll
    for (int hp = 0; hp < 2; ++hp) {
      const int hh = hbase + hp;
#pragma unroll
      for (int it = 0; it < 2; ++it)
#pragma unroll
        for (int r = 0; r < 4; ++r) {
          const float inv = 1.f / lac[hp][it][r];
          const size_t irow = i0 + it * 16 + q * 4 + r;
#pragma unroll
          for (int ft = 0; ft < 2; ++ft)
            out[irow * CC + hh * 32 + ft * 16 + il] =
                acc[hp][it][ft][r] * inv;
        }
    }
  } else {
#pragma unroll
    for (int hp = 0; hp < 2; ++hp) {
      const int hh = hbase + hp;
#pragma unroll
      for (int it = 0; it < 2; ++it)
#pragma unroll
        for (int r = 0; r < 4; ++r) {
          const size_t irow = i0 + it * 16 + q * 4 + r;
          if (il == 0)
            l_ws[((size_t)sp * NH + hh) * NN + irow] = lac[hp][it][r];
#pragma unroll
          for (int ft = 0; ft < 2; ++ft)
            acc_ws[((size_t)sp * NN + irow) * CC + hh * 32 + ft * 16 + il] =
                acc[hp][it][ft][r];
        }
    }
  }
}

// ---------------- K3: combine split partials ----------------
__global__ __launch_bounds__(256) void k_combine(
    const float* __restrict__ acc_ws, const float* __restrict__ l_ws,
    float* __restrict__ out, const int splits) {
  const int idx = blockIdx.x * 256 + threadIdx.x;  // float4 index
  const int row = idx >> 6, c4 = idx & 63;
  const int hh = c4 >> 3;
  float ax = 0.f, ay = 0.f, az = 0.f, aw = 0.f, l = 0.f;
  for (int s = 0; s < splits; ++s) {
    const float4 v =
        *(const float4*)&acc_ws[((size_t)s * NN + row) * CC + c4 * 4];
    ax += v.x; ay += v.y; az += v.z; aw += v.w;
    l += l_ws[((size_t)s * NH + hh) * NN + row];
  }
  const float inv = 1.f / l;
  *(float4*)&out[(size_t)row * CC + c4 * 4] =
      make_float4(ax * inv, ay * inv, az * inv, aw * inv);
}

extern "C" void kernel_launch(void* const* d_in, const int* in_sizes, int n_in,
                              void* d_out, int out_size, void* d_ws,
                              size_t ws_size, hipStream_t stream) {
  (void)in_sizes; (void)n_in; (void)out_size;
  const float* h = (const float*)d_in[0];
  const int* adj = (const int*)d_in[1];
  const float* W = (const float*)d_in[2];
  const float* a = (const float*)d_in[3];
  float* out = (float*)d_out;
  char* ws = (char*)d_ws;

  unsigned short* gT = (unsigned short*)ws;               // 2 MB
  float4* spack = (float4*)(ws + (size_t)NN * CC * 2);    // 512 KB
  float* dtrip = (float*)(spack + (size_t)NH * NN);       // 384 KB (blocked)
  char* after = (char*)(dtrip + (size_t)NH * (NN / 8) * 24);
  const size_t base = (size_t)(after - ws);
  const size_t per_split = (size_t)NN * CC * 4 + (size_t)NH * NN * 4;

  int splits = 1;
  if (ws_size >= base + 8 * per_split) splits = 8;
  else if (ws_size >= base + 4 * per_split) splits = 4;
  else if (ws_size >= base + 2 * per_split) splits = 2;

  k_gemm<<<NN / GROWS, 256, 0, stream>>>(h, W, a, gT, spack, dtrip);

  const int nblk = (NN / 32) * splits;
  if (splits == 1) {
    k_attn<<<nblk, 256, 0, stream>>>(adj, gT, spack, dtrip, nullptr, nullptr,
                                     out, 1, 1);
  } else {
    float* acc_ws = (float*)after;
    float* l_ws = acc_ws + (size_t)splits * NN * CC;
    k_attn<<<nblk, 256, 0, stream>>>(adj, gT, spack, dtrip, acc_ws, l_ws, out,
                                     splits, 0);
    k_combine<<<NN * CC / 4 / 256, 256, 0, stream>>>(acc_ws, l_ws, out,
                                                     splits);
  }
}

// Round 7
// 80.490 us; speedup vs baseline: 1.4201x; 1.4201x over previous
//
#include <hip/hip_runtime.h>

#define NN 4096
#define FIN 256
#define CC 256
#define NH 8

typedef __attribute__((ext_vector_type(8))) short short8;
typedef __attribute__((ext_vector_type(4))) float f32x4;
typedef __attribute__((ext_vector_type(4))) unsigned int u32x4;

__device__ __forceinline__ unsigned cvtpk_bf16(float lo, float hi) {
  unsigned r;
  asm("v_cvt_pk_bf16_f32 %0, %1, %2" : "=v"(r) : "v"(lo), "v"(hi));
  return r;
}

__device__ __forceinline__ unsigned short bf16rn(float x) {
  unsigned int u = __builtin_bit_cast(unsigned int, x);
  u += 0x7fffu + ((u >> 16) & 1u);
  return (unsigned short)(u >> 16);
}

__device__ __forceinline__ void gl_lds16(const void* g, void* l) {
  __builtin_amdgcn_global_load_lds(
      (const __attribute__((address_space(1))) void*)g,
      (__attribute__((address_space(3))) void*)l, 16, 0, 0);
}

// ---------------- K1: g = h@W, fused epilogue ----------------
// writes gT (bf16, [c=h*32+f][n]), spack[h][n]=(s_src, e^s, e^.2s, 0),
// dtrip planes [3][h][n] = (-s_dst, e^sd, e^{0.2 sd})
#define GROWS 8
__global__ __launch_bounds__(256) void k_gemm(
    const float* __restrict__ h, const float* __restrict__ W,
    const float* __restrict__ a, unsigned short* __restrict__ gT,
    float4* __restrict__ spack, float* __restrict__ dtrip) {
  __shared__ float hs[GROWS][FIN];
  const int r0 = blockIdx.x * GROWS;
  const int t = threadIdx.x;
#pragma unroll
  for (int idx = t; idx < GROWS * FIN / 4; idx += 256) {
    const int r = idx >> 6, c4 = idx & 63;
    *(float4*)&hs[r][c4 * 4] =
        *(const float4*)&h[(size_t)(r0 + r) * FIN + c4 * 4];
  }
  __syncthreads();
  const int c = t;
  float acc[GROWS];
#pragma unroll
  for (int r = 0; r < GROWS; ++r) acc[r] = 0.f;
  for (int k = 0; k < FIN; k += 4) {
    const float w0 = W[(size_t)(k + 0) * CC + c];
    const float w1 = W[(size_t)(k + 1) * CC + c];
    const float w2 = W[(size_t)(k + 2) * CC + c];
    const float w3 = W[(size_t)(k + 3) * CC + c];
#pragma unroll
    for (int r = 0; r < GROWS; ++r) {
      const float4 hv = *(const float4*)&hs[r][k];
      acc[r] += hv.x * w0 + hv.y * w1 + hv.z * w2 + hv.w * w3;
    }
  }
  const int f = c & 31, hh = c >> 5;
  const float aS = a[f], aD = a[32 + f];
  unsigned short gu[GROWS];
#pragma unroll
  for (int r = 0; r < GROWS; ++r) {
    float ps = acc[r] * aS, pd = acc[r] * aD;
#pragma unroll
    for (int m = 1; m < 32; m <<= 1) {
      ps += __shfl_xor(ps, m, 64);
      pd += __shfl_xor(pd, m, 64);
    }
    if (f == 0) {
      const int n = r0 + r;
      spack[(size_t)hh * NN + n] =
          make_float4(ps, __expf(ps), __expf(0.2f * ps), 0.f);
      dtrip[(size_t)hh * NN + n] = -pd;
      dtrip[(size_t)NH * NN + (size_t)hh * NN + n] = __expf(pd);
      dtrip[2 * (size_t)NH * NN + (size_t)hh * NN + n] = __expf(0.2f * pd);
    }
    gu[r] = bf16rn(acc[r]);
  }
  uint4 gv;
  gv.x = (unsigned)gu[0] | ((unsigned)gu[1] << 16);
  gv.y = (unsigned)gu[2] | ((unsigned)gu[3] << 16);
  gv.z = (unsigned)gu[4] | ((unsigned)gu[5] << 16);
  gv.w = (unsigned)gu[6] | ((unsigned)gu[7] << 16);
  *(uint4*)(gT + (size_t)c * NN + r0) = gv;
}

// ---------------- K2: LDS double-buffered fused masked-softmax + MFMA PV ----
// 256 thr = 4 waves; wave w -> heads {2w,2w+1}, i-block 32 rows, j-split sp.
// Per 32-j chunk: stage {gT 16KB, dtrip 3KB, adj 4KB} via global_load_lds
// into buf[cur^1] (issued BEFORE compute), compute from buf[cur], one
// __syncthreads (drains vmcnt+lgkm) per chunk. T3-minimal 2-phase.
struct Buf {
  unsigned short gt[256][32];  // 16 KB  [c][j]
  float dt[3][NH][32];         // 3 KB   [plane][h][j]
  int aj[32][32];              // 4 KB   [i][j]
};

__global__ __launch_bounds__(256, 2) void k_attn(
    const int* __restrict__ adj, const unsigned short* __restrict__ gT,
    const float4* __restrict__ spack, const float* __restrict__ dtrip,
    float* __restrict__ acc_ws, float* __restrict__ l_ws,
    float* __restrict__ out, const int splits, const int direct) {
  __shared__ Buf buf[2];  // 47 KB

  const int lane = threadIdx.x & 63;
  const int w = threadIdx.x >> 6;
  const int il = lane & 15, q = lane >> 4;
  const int bx = blockIdx.x;
  const int sp = bx & (splits - 1);
  const int ib = bx / splits;
  const int i0 = ib * 32;
  const int jrange = NN / splits, j0b = sp * jrange;
  const int hbase = w * 2;

  // hoisted i-side scalars
  float ssv[2][2], e1v[2][2], e2v[2][2];
#pragma unroll
  for (int hp = 0; hp < 2; ++hp)
#pragma unroll
    for (int it = 0; it < 2; ++it) {
      const float4 v = spack[(size_t)(hbase + hp) * NN + i0 + it * 16 + il];
      ssv[hp][it] = v.x; e1v[hp][it] = v.y; e2v[hp][it] = v.z;
    }

  f32x4 acc[2][2][2];
  f32x4 lac[2][2];
#pragma unroll
  for (int hp = 0; hp < 2; ++hp)
#pragma unroll
    for (int it = 0; it < 2; ++it) {
#pragma unroll
      for (int r = 0; r < 4; ++r) lac[hp][it][r] = 0.f;
#pragma unroll
      for (int ft = 0; ft < 2; ++ft)
#pragma unroll
        for (int r = 0; r < 4; ++r) acc[hp][it][ft][r] = 0.f;
    }

  const short8 ones = {(short)0x3F80, (short)0x3F80, (short)0x3F80,
                       (short)0x3F80, (short)0x3F80, (short)0x3F80,
                       (short)0x3F80, (short)0x3F80};

  // ---- staging: wave-uniform LDS bases + per-lane global addresses ----
  auto stage = [&](Buf* b, int j0) {
    // gT chunk: 16 KB = 1024 x 16B units; unit u -> c=u>>2, part=u&3
#pragma unroll
    for (int r = 0; r < 4; ++r) {
      const int base = r * 256 + w * 64;  // wave-uniform
      const int u = base + lane;
      gl_lds16(gT + (size_t)(u >> 2) * NN + j0 + (u & 3) * 8,
               (char*)&b->gt[0][0] + (size_t)base * 16);
    }
    // adj chunk: 4 KB = 256 units; unit u -> row=u>>3, seg=u&7
    {
      const int base = w * 64;
      const int u = base + lane;
      gl_lds16(adj + (size_t)(i0 + (u >> 3)) * NN + j0 + (u & 7) * 4,
               (char*)&b->aj[0][0] + (size_t)base * 16);
    }
    // dtrip: 3 planes x 1KB; wave p<3 stages plane p: lane -> h=l>>3, k=l&7
    if (w < 3) {
      gl_lds16(dtrip + (size_t)w * NH * NN + (size_t)(lane >> 3) * NN + j0 +
                   (lane & 7) * 4,
               (char*)&b->dt[0][0][0] + (size_t)(w * 64) * 16);
    }
  };

  const int nch = jrange / 32;
  stage(&buf[0], j0b);
  __syncthreads();
  int cur = 0;

  for (int jc = 0; jc < nch; ++jc) {
    if (jc + 1 < nch) stage(&buf[cur ^ 1], j0b + (jc + 1) * 32);
    const Buf* bc = &buf[cur];

    // adj -> float multipliers (from LDS)
    float adf[2][8];
#pragma unroll
    for (int it = 0; it < 2; ++it) {
      int av[8];
      *(int4*)&av[0] = *(const int4*)&bc->aj[it * 16 + il][q * 8];
      *(int4*)&av[4] = *(const int4*)&bc->aj[it * 16 + il][q * 8 + 4];
#pragma unroll
      for (int e = 0; e < 8; ++e) adf[it][e] = (float)av[e];
    }

#pragma unroll
    for (int hp = 0; hp < 2; ++hp) {
      const int hh = hbase + hp;
      float nsd[8], e1j[8], e2j[8];
      *(float4*)&nsd[0] = *(const float4*)&bc->dt[0][hh][q * 8];
      *(float4*)&nsd[4] = *(const float4*)&bc->dt[0][hh][q * 8 + 4];
      *(float4*)&e1j[0] = *(const float4*)&bc->dt[1][hh][q * 8];
      *(float4*)&e1j[4] = *(const float4*)&bc->dt[1][hh][q * 8 + 4];
      *(float4*)&e2j[0] = *(const float4*)&bc->dt[2][hh][q * 8];
      *(float4*)&e2j[4] = *(const float4*)&bc->dt[2][hh][q * 8 + 4];
      const short8 b0 = *(const short8*)&bc->gt[hh * 32 + il][q * 8];
      const short8 b1 = *(const short8*)&bc->gt[hh * 32 + 16 + il][q * 8];
#pragma unroll
      for (int it = 0; it < 2; ++it) {
        const float ssl = ssv[hp][it];
        const float ei1 = e1v[hp][it], ei2 = e2v[hp][it];
        float wv[8];
#pragma unroll
        for (int e = 0; e < 8; ++e) {
          const bool pos = ssl > nsd[e];
          wv[e] = (pos ? ei1 : ei2) * (pos ? e1j[e] : e2j[e]) * adf[it][e];
        }
        u32x4 uu;
#pragma unroll
        for (int m = 0; m < 4; ++m)
          uu[m] = cvtpk_bf16(wv[2 * m], wv[2 * m + 1]);
        const short8 afr = __builtin_bit_cast(short8, uu);
        acc[hp][it][0] = __builtin_amdgcn_mfma_f32_16x16x32_bf16(
            afr, b0, acc[hp][it][0], 0, 0, 0);
        acc[hp][it][1] = __builtin_amdgcn_mfma_f32_16x16x32_bf16(
            afr, b1, acc[hp][it][1], 0, 0, 0);
        lac[hp][it] = __builtin_amdgcn_mfma_f32_16x16x32_bf16(
            afr, ones, lac[hp][it], 0, 0, 0);
      }
    }
    __syncthreads();  // drains vmcnt (staging) + lgkm (reads); swap safe
    cur ^= 1;
  }

  if (direct) {
#pragma unroll
    for (int hp = 0; hp < 2; ++hp) {
      const int hh = hbase + hp;
#pragma unroll
      for (int it = 0; it < 2; ++it)
#pragma unroll
        for (int r = 0; r < 4; ++r) {
          const float inv = 1.f / lac[hp][it][r];
          const size_t irow = i0 + it * 16 + q * 4 + r;
#pragma unroll
          for (int ft = 0; ft < 2; ++ft)
            out[irow * CC + hh * 32 + ft * 16 + il] =
                acc[hp][it][ft][r] * inv;
        }
    }
  } else {
#pragma unroll
    for (int hp = 0; hp < 2; ++hp) {
      const int hh = hbase + hp;
#pragma unroll
      for (int it = 0; it < 2; ++it)
#pragma unroll
        for (int r = 0; r < 4; ++r) {
          const size_t irow = i0 + it * 16 + q * 4 + r;
          if (il == 0)
            l_ws[((size_t)sp * NH + hh) * NN + irow] = lac[hp][it][r];
#pragma unroll
          for (int ft = 0; ft < 2; ++ft)
            acc_ws[((size_t)sp * NN + irow) * CC + hh * 32 + ft * 16 + il] =
                acc[hp][it][ft][r];
        }
    }
  }
}

// ---------------- K3: combine split partials ----------------
__global__ __launch_bounds__(256) void k_combine(
    const float* __restrict__ acc_ws, const float* __restrict__ l_ws,
    float* __restrict__ out, const int splits) {
  const int idx = blockIdx.x * 256 + threadIdx.x;  // float4 index
  const int row = idx >> 6, c4 = idx & 63;
  const int hh = c4 >> 3;
  float ax = 0.f, ay = 0.f, az = 0.f, aw = 0.f, l = 0.f;
  for (int s = 0; s < splits; ++s) {
    const float4 v =
        *(const float4*)&acc_ws[((size_t)s * NN + row) * CC + c4 * 4];
    ax += v.x; ay += v.y; az += v.z; aw += v.w;
    l += l_ws[((size_t)s * NH + hh) * NN + row];
  }
  const float inv = 1.f / l;
  *(float4*)&out[(size_t)row * CC + c4 * 4] =
      make_float4(ax * inv, ay * inv, az * inv, aw * inv);
}

extern "C" void kernel_launch(void* const* d_in, const int* in_sizes, int n_in,
                              void* d_out, int out_size, void* d_ws,
                              size_t ws_size, hipStream_t stream) {
  (void)in_sizes; (void)n_in; (void)out_size;
  const float* h = (const float*)d_in[0];
  const int* adj = (const int*)d_in[1];
  const float* W = (const float*)d_in[2];
  const float* a = (const float*)d_in[3];
  float* out = (float*)d_out;
  char* ws = (char*)d_ws;

  unsigned short* gT = (unsigned short*)ws;               // 2 MB
  float4* spack = (float4*)(ws + (size_t)NN * CC * 2);    // 512 KB
  float* dtrip = (float*)(spack + (size_t)NH * NN);       // 384 KB (3 planes)
  char* after = (char*)(dtrip + 3 * (size_t)NH * NN);
  const size_t base = (size_t)(after - ws);
  const size_t per_split = (size_t)NN * CC * 4 + (size_t)NH * NN * 4;

  int splits = 1;
  if (ws_size >= base + 8 * per_split) splits = 8;
  else if (ws_size >= base + 4 * per_split) splits = 4;
  else if (ws_size >= base + 2 * per_split) splits = 2;

  k_gemm<<<NN / GROWS, 256, 0, stream>>>(h, W, a, gT, spack, dtrip);

  const int nblk = (NN / 32) * splits;
  if (splits == 1) {
    k_attn<<<nblk, 256, 0, stream>>>(adj, gT, spack, dtrip, nullptr, nullptr,
                                     out, 1, 1);
  } else {
    float* acc_ws = (float*)after;
    float* l_ws = acc_ws + (size_t)splits * NN * CC;
    k_attn<<<nblk, 256, 0, stream>>>(adj, gT, spack, dtrip, acc_ws, l_ws, out,
                                     splits, 0);
    k_combine<<<NN * CC / 4 / 256, 256, 0, stream>>>(acc_ws, l_ws, out,
                                                     splits);
  }
}